// Round 1
// baseline (4239.075 us; speedup 1.0000x reference)
//
#include <hip/hip_runtime.h>

// ---------------------------------------------------------------------------
// 2-layer GCN forward.  Layout of d_ws (floats):
//   dinv  [N]          (deg accumulated here first, then rsqrt in place)
//   h     [N*128]      (x@W1; later reused: h2 [N*64] | agg2 [N*64])
//   agg1  [N*128]      (edge aggregation layer 1; relu'd h1 written in place)
// Total = 257*N floats ~= 103 MB.
// Self-loops handled analytically: agg_full[i] = agg_edges[i] + dinv[i]^2*h[i].
// ---------------------------------------------------------------------------

__global__ void deg_kernel(const int* __restrict__ tgt, float* __restrict__ deg, int E) {
    int t = blockIdx.x * blockDim.x + threadIdx.x;
    if (t < E) atomicAdd(&deg[tgt[t]], 1.0f);
}

__global__ void dinv_kernel(float* __restrict__ deg, int N) {
    int t = blockIdx.x * blockDim.x + threadIdx.x;
    if (t < N) deg[t] = rsqrtf(deg[t] + 1.0f);   // +1 = self-loop
}

// C[N,M] = A[N,128] @ W[128,M], row-major fp32. 4x4 microtile per thread.
// Block: 256 threads -> tile ROWS x M.  aT staged transposed so the inner
// loop is 2x ds_read_b128 + 16 v_fma (FMA-issue bound).
template <int M, int ROWS>
__global__ __launch_bounds__(256) void gemm_fp32(const float* __restrict__ A,
                                                 const float* __restrict__ W,
                                                 float* __restrict__ C, int N) {
    __shared__ float wS[64 * M];     // W[kt..kt+64, 0..M)
    __shared__ float aT[64 * ROWS];  // transposed: aT[k*ROWS + r]
    const int tid  = threadIdx.x;
    const int row0 = blockIdx.x * ROWS;
    const int c4   = (tid % (M / 4)) * 4;
    const int r0   = (tid / (M / 4)) * 4;

    float acc[4][4] = {};

    for (int kt = 0; kt < 128; kt += 64) {
        // stage W tile (coalesced float4)
        for (int i = tid * 4; i < 64 * M; i += 256 * 4) {
            *(float4*)&wS[i] = *(const float4*)&W[(kt + i / M) * M + (i % M)];
        }
        // stage A tile, transposed on the fly
        for (int i = tid * 4; i < ROWS * 64; i += 256 * 4) {
            int r = i / 64, k = i % 64;
            int row = row0 + r;
            if (row >= N) row = N - 1;  // clamp (stores are guarded)
            float4 a = *(const float4*)&A[row * 128 + kt + k];
            aT[(k + 0) * ROWS + r] = a.x;
            aT[(k + 1) * ROWS + r] = a.y;
            aT[(k + 2) * ROWS + r] = a.z;
            aT[(k + 3) * ROWS + r] = a.w;
        }
        __syncthreads();
#pragma unroll 16
        for (int k = 0; k < 64; ++k) {
            float4 av = *(const float4*)&aT[k * ROWS + r0];
            float4 wv = *(const float4*)&wS[k * M + c4];
            float a4[4] = {av.x, av.y, av.z, av.w};
            float w4[4] = {wv.x, wv.y, wv.z, wv.w};
#pragma unroll
            for (int i = 0; i < 4; ++i)
#pragma unroll
                for (int j = 0; j < 4; ++j) acc[i][j] += a4[i] * w4[j];
        }
        __syncthreads();
    }
#pragma unroll
    for (int i = 0; i < 4; ++i) {
        int row = row0 + r0 + i;
        if (row < N) {
            float4 v = make_float4(acc[i][0], acc[i][1], acc[i][2], acc[i][3]);
            *(float4*)&C[row * M + c4] = v;
        }
    }
}

// Per (edge, 4-feature) thread: agg[tgt] += dinv[src]*dinv[tgt] * h[src]
template <int D>
__global__ void scatter_kernel(const float* __restrict__ h, const int* __restrict__ src,
                               const int* __restrict__ tgt, const float* __restrict__ dinv,
                               float* __restrict__ agg, int E) {
    constexpr int F4 = D / 4;  // float4 groups per row
    long long t = (long long)blockIdx.x * blockDim.x + threadIdx.x;
    int e = (int)(t / F4);
    if (e >= E) return;
    int f = (int)(t % F4) * 4;
    int s = src[e], d = tgt[e];
    float w = dinv[s] * dinv[d];
    float4 hv = *(const float4*)&h[(long long)s * D + f];
    float* a = &agg[(long long)d * D + f];
    atomicAdd(a + 0, w * hv.x);
    atomicAdd(a + 1, w * hv.y);
    atomicAdd(a + 2, w * hv.z);
    atomicAdd(a + 3, w * hv.w);
}

// h1 = relu(agg1 + dinv^2 * h + b1), written in place into agg1.  D=128.
__global__ void relu_bias_kernel(float* __restrict__ agg, const float* __restrict__ h,
                                 const float* __restrict__ dinv, const float* __restrict__ b,
                                 int N) {
    int t = blockIdx.x * blockDim.x + threadIdx.x;  // N*32 threads
    if (t >= N * 32) return;
    int node = t >> 5;
    int f = (t & 31) << 2;
    float di = dinv[node];
    float w = di * di;
    float4 a  = *(float4*)&agg[(long long)node * 128 + f];
    float4 hv = *(const float4*)&h[(long long)node * 128 + f];
    float4 bv = *(const float4*)&b[f];
    a.x = fmaxf(a.x + w * hv.x + bv.x, 0.0f);
    a.y = fmaxf(a.y + w * hv.y + bv.y, 0.0f);
    a.z = fmaxf(a.z + w * hv.z + bv.z, 0.0f);
    a.w = fmaxf(a.w + w * hv.w + bv.w, 0.0f);
    *(float4*)&agg[(long long)node * 128 + f] = a;
}

// out = agg2 + dinv^2 * h2 + b2.  D=64.
__global__ void final_kernel(const float* __restrict__ agg, const float* __restrict__ h2,
                             const float* __restrict__ dinv, const float* __restrict__ b,
                             float* __restrict__ out, int N) {
    int t = blockIdx.x * blockDim.x + threadIdx.x;  // N*16 threads
    if (t >= N * 16) return;
    int node = t >> 4;
    int f = (t & 15) << 2;
    float di = dinv[node];
    float w = di * di;
    float4 a  = *(const float4*)&agg[(long long)node * 64 + f];
    float4 hv = *(const float4*)&h2[(long long)node * 64 + f];
    float4 bv = *(const float4*)&b[f];
    float4 o = make_float4(a.x + w * hv.x + bv.x, a.y + w * hv.y + bv.y,
                           a.z + w * hv.z + bv.z, a.w + w * hv.w + bv.w);
    *(float4*)&out[(long long)node * 64 + f] = o;
}

extern "C" void kernel_launch(void* const* d_in, const int* in_sizes, int n_in,
                              void* d_out, int out_size, void* d_ws, size_t ws_size,
                              hipStream_t stream) {
    const float* x  = (const float*)d_in[0];
    const int*   ei = (const int*)d_in[1];
    const float* W1 = (const float*)d_in[2];
    const float* b1 = (const float*)d_in[3];
    const float* W2 = (const float*)d_in[4];
    const float* b2 = (const float*)d_in[5];
    float* out = (float*)d_out;

    const int N = in_sizes[0] / 128;
    const int E = in_sizes[1] / 2;
    const int* src = ei;
    const int* tgt = ei + E;

    float* ws   = (float*)d_ws;
    float* dinv = ws;                         // N
    float* h    = ws + N;                     // N*128
    float* agg1 = ws + N + (size_t)N * 128;   // N*128
    float* h2   = h;                          // N*64   (reuse after relu)
    float* agg2 = h + (size_t)N * 64;         // N*64   (reuse after relu)

    hipMemsetAsync(dinv, 0, (size_t)N * sizeof(float), stream);
    hipMemsetAsync(agg1, 0, (size_t)N * 128 * sizeof(float), stream);

    deg_kernel<<<(E + 255) / 256, 256, 0, stream>>>(tgt, dinv, E);
    dinv_kernel<<<(N + 255) / 256, 256, 0, stream>>>(dinv, N);

    // Layer 1: h = x @ W1
    gemm_fp32<128, 32><<<(N + 31) / 32, 256, 0, stream>>>(x, W1, h, N);
    {
        long long threads = (long long)E * 32;
        scatter_kernel<128><<<(int)((threads + 255) / 256), 256, 0, stream>>>(
            h, src, tgt, dinv, agg1, E);
    }
    relu_bias_kernel<<<(N * 32 + 255) / 256, 256, 0, stream>>>(agg1, h, dinv, b1, N);

    // Layer 2: h2 = h1 @ W2   (h1 lives in agg1)
    gemm_fp32<64, 64><<<(N + 63) / 64, 256, 0, stream>>>(agg1, W2, h2, N);
    hipMemsetAsync(agg2, 0, (size_t)N * 64 * sizeof(float), stream);
    {
        long long threads = (long long)E * 16;
        scatter_kernel<64><<<(int)((threads + 255) / 256), 256, 0, stream>>>(
            h2, src, tgt, dinv, agg2, E);
    }
    final_kernel<<<(N * 16 + 255) / 256, 256, 0, stream>>>(agg2, h2, dinv, b2, out, N);
}

// Round 2
// 624.163 us; speedup vs baseline: 6.7916x; 6.7916x over previous
//
#include <hip/hip_runtime.h>

// ---------------------------------------------------------------------------
// 2-layer GCN forward, pull-mode (atomic-free aggregation).
//
// Per call: build CSR of incoming edges (deg count -> scan -> fill), then
// per-node wave gathers  out[v] = dinv[v]*(sum_e dinv[s]*h[s] + dinv[v]*h[v]) + b
// with bias/ReLU fused.  No fp32 atomics anywhere.
//
// ws layout (4-byte elems, N=100000 divisible by 4, E=1600000):
//   dinv    float[N]
//   deg     int[N]
//   rowptr  int[N+4]
//   cursor  int[N]
//   bsum    int[128]
//   csr_src int[E]
//   h       float[N*128]   (x@W1; reused as h2 [N*64] after layer 1)
//   h1      float[N*128]
// total ~= 110 MB.
// ---------------------------------------------------------------------------

__global__ void deg_count_kernel(const int* __restrict__ tgt, int* __restrict__ deg, int E) {
    int t = blockIdx.x * blockDim.x + threadIdx.x;
    if (t < E) atomicAdd(&deg[tgt[t]], 1);
}

__global__ void dinv_kernel(const int* __restrict__ deg, float* __restrict__ dinv, int N) {
    int t = blockIdx.x * blockDim.x + threadIdx.x;
    if (t < N) dinv[t] = rsqrtf((float)deg[t] + 1.0f);  // +1 = self-loop
}

// ---- 3-kernel exclusive scan over deg[N] -> rowptr[N] (items/block = 1024) ----
__global__ __launch_bounds__(256) void scan_partial(const int* __restrict__ deg,
                                                    int* __restrict__ bsum, int N) {
    int t = threadIdx.x, b = blockIdx.x;
    int base = b * 1024 + t * 4;
    int s = 0;
#pragma unroll
    for (int k = 0; k < 4; ++k) s += (base + k < N) ? deg[base + k] : 0;
    // wave reduce
#pragma unroll
    for (int off = 32; off > 0; off >>= 1) s += __shfl_down(s, off, 64);
    __shared__ int ws[4];
    if ((t & 63) == 0) ws[t >> 6] = s;
    __syncthreads();
    if (t == 0) bsum[b] = ws[0] + ws[1] + ws[2] + ws[3];
}

__global__ void scan_bsum(int* __restrict__ bsum, int nb) {
    __shared__ int s[128];
    int t = threadIdx.x;  // 128 threads
    int v = (t < nb) ? bsum[t] : 0;
    s[t] = v;
    __syncthreads();
    for (int off = 1; off < 128; off <<= 1) {
        int u = (t >= off) ? s[t - off] : 0;
        __syncthreads();
        s[t] += u;
        __syncthreads();
    }
    if (t < nb) bsum[t] = s[t] - v;  // exclusive
}

__global__ __launch_bounds__(256) void scan_final(const int* __restrict__ deg,
                                                  const int* __restrict__ bsum,
                                                  int* __restrict__ rowptr, int N, int E) {
    int t = threadIdx.x, b = blockIdx.x;
    int base = b * 1024 + t * 4;
    int d[4];
#pragma unroll
    for (int k = 0; k < 4; ++k) d[k] = (base + k < N) ? deg[base + k] : 0;
    int tot = d[0] + d[1] + d[2] + d[3];
    int incl = tot;
    int lane = t & 63, wid = t >> 6;
#pragma unroll
    for (int off = 1; off < 64; off <<= 1) {
        int u = __shfl_up(incl, off, 64);
        if (lane >= off) incl += u;
    }
    __shared__ int wsum[4];
    if (lane == 63) wsum[wid] = incl;
    __syncthreads();
    int woff = 0;
    for (int w = 0; w < wid; ++w) woff += wsum[w];
    int run = incl - tot + woff + bsum[b];
#pragma unroll
    for (int k = 0; k < 4; ++k) {
        if (base + k < N) rowptr[base + k] = run;
        run += d[k];
    }
    if (b == gridDim.x - 1 && t == 255) rowptr[N] = E;
}

__global__ void init_cursor(const int* __restrict__ rowptr, int* __restrict__ cursor, int N) {
    int t = blockIdx.x * blockDim.x + threadIdx.x;
    if (t < N) cursor[t] = rowptr[t];
}

__global__ void fill_csr(const int* __restrict__ src, const int* __restrict__ tgt,
                         int* __restrict__ cursor, int* __restrict__ csr_src, int E) {
    int t = blockIdx.x * blockDim.x + threadIdx.x;
    if (t < E) {
        int pos = atomicAdd(&cursor[tgt[t]], 1);
        csr_src[pos] = src[t];
    }
}

// ---- C[N,M] = A[N,128] @ W[128,M], fp32, 4x4 microtile (unchanged from R1) ----
template <int M, int ROWS>
__global__ __launch_bounds__(256) void gemm_fp32(const float* __restrict__ A,
                                                 const float* __restrict__ W,
                                                 float* __restrict__ C, int N) {
    __shared__ float wS[64 * M];
    __shared__ float aT[64 * ROWS];
    const int tid  = threadIdx.x;
    const int row0 = blockIdx.x * ROWS;
    const int c4   = (tid % (M / 4)) * 4;
    const int r0   = (tid / (M / 4)) * 4;
    float acc[4][4] = {};

    for (int kt = 0; kt < 128; kt += 64) {
        for (int i = tid * 4; i < 64 * M; i += 256 * 4)
            *(float4*)&wS[i] = *(const float4*)&W[(kt + i / M) * M + (i % M)];
        for (int i = tid * 4; i < ROWS * 64; i += 256 * 4) {
            int r = i / 64, k = i % 64;
            int row = row0 + r;
            if (row >= N) row = N - 1;
            float4 a = *(const float4*)&A[row * 128 + kt + k];
            aT[(k + 0) * ROWS + r] = a.x;
            aT[(k + 1) * ROWS + r] = a.y;
            aT[(k + 2) * ROWS + r] = a.z;
            aT[(k + 3) * ROWS + r] = a.w;
        }
        __syncthreads();
#pragma unroll 16
        for (int k = 0; k < 64; ++k) {
            float4 av = *(const float4*)&aT[k * ROWS + r0];
            float4 wv = *(const float4*)&wS[k * M + c4];
            float a4[4] = {av.x, av.y, av.z, av.w};
            float w4[4] = {wv.x, wv.y, wv.z, wv.w};
#pragma unroll
            for (int i = 0; i < 4; ++i)
#pragma unroll
                for (int j = 0; j < 4; ++j) acc[i][j] += a4[i] * w4[j];
        }
        __syncthreads();
    }
#pragma unroll
    for (int i = 0; i < 4; ++i) {
        int row = row0 + r0 + i;
        if (row < N)
            *(float4*)&C[row * M + c4] =
                make_float4(acc[i][0], acc[i][1], acc[i][2], acc[i][3]);
    }
}

// ---- pull-mode gather: one wave per node, fused self-loop + bias (+ relu) ----
template <int D, bool RELU>
__global__ __launch_bounds__(256) void gather_kernel(
    const float* __restrict__ h, const int* __restrict__ rowptr,
    const int* __restrict__ csr_src, const float* __restrict__ dinv,
    const float* __restrict__ bias, float* __restrict__ out, int N) {
    constexpr int PL = D / 64;  // floats per lane (2 for D=128, 1 for D=64)
    const int wid = threadIdx.x >> 6, lane = threadIdx.x & 63;
    const int node = blockIdx.x * 4 + wid;
    if (node >= N) return;
    const int beg = rowptr[node], end = rowptr[node + 1];
    const int col = lane * PL;
    float acc0 = 0.f, acc1 = 0.f;

    int j = beg;
    for (; j + 4 <= end; j += 4) {  // unroll x4 for memory-level parallelism
        int s0 = csr_src[j + 0], s1 = csr_src[j + 1];
        int s2 = csr_src[j + 2], s3 = csr_src[j + 3];
        float w0 = dinv[s0], w1 = dinv[s1], w2 = dinv[s2], w3 = dinv[s3];
        if constexpr (PL == 2) {
            float2 v0 = *(const float2*)&h[(size_t)s0 * D + col];
            float2 v1 = *(const float2*)&h[(size_t)s1 * D + col];
            float2 v2 = *(const float2*)&h[(size_t)s2 * D + col];
            float2 v3 = *(const float2*)&h[(size_t)s3 * D + col];
            acc0 += w0 * v0.x + w1 * v1.x + w2 * v2.x + w3 * v3.x;
            acc1 += w0 * v0.y + w1 * v1.y + w2 * v2.y + w3 * v3.y;
        } else {
            acc0 += w0 * h[(size_t)s0 * D + col] + w1 * h[(size_t)s1 * D + col] +
                    w2 * h[(size_t)s2 * D + col] + w3 * h[(size_t)s3 * D + col];
        }
    }
    for (; j < end; ++j) {
        int s = csr_src[j];
        float w = dinv[s];
        if constexpr (PL == 2) {
            float2 v = *(const float2*)&h[(size_t)s * D + col];
            acc0 += w * v.x;
            acc1 += w * v.y;
        } else {
            acc0 += w * h[(size_t)s * D + col];
        }
    }

    const float di = dinv[node];
    if constexpr (PL == 2) {
        float2 hv = *(const float2*)&h[(size_t)node * D + col];
        acc0 += di * hv.x;
        acc1 += di * hv.y;
        float r0 = di * acc0 + bias[col];
        float r1 = di * acc1 + bias[col + 1];
        if (RELU) { r0 = fmaxf(r0, 0.f); r1 = fmaxf(r1, 0.f); }
        *(float2*)&out[(size_t)node * D + col] = make_float2(r0, r1);
    } else {
        acc0 += di * h[(size_t)node * D + col];
        float r0 = di * acc0 + bias[col];
        if (RELU) r0 = fmaxf(r0, 0.f);
        out[(size_t)node * D + col] = r0;
    }
}

extern "C" void kernel_launch(void* const* d_in, const int* in_sizes, int n_in,
                              void* d_out, int out_size, void* d_ws, size_t ws_size,
                              hipStream_t stream) {
    const float* x  = (const float*)d_in[0];
    const int*   ei = (const int*)d_in[1];
    const float* W1 = (const float*)d_in[2];
    const float* b1 = (const float*)d_in[3];
    const float* W2 = (const float*)d_in[4];
    const float* b2 = (const float*)d_in[5];
    float* out = (float*)d_out;

    const int N = in_sizes[0] / 128;
    const int E = in_sizes[1] / 2;
    const int* src = ei;
    const int* tgt = ei + E;

    float* ws      = (float*)d_ws;
    float* dinv    = ws;                       // N
    int*   deg     = (int*)(ws + N);           // N
    int*   rowptr  = deg + N;                  // N+4
    int*   cursor  = rowptr + N + 4;           // N
    int*   bsum    = cursor + N;               // 128
    int*   csr_src = bsum + 128;               // E
    float* h       = (float*)(csr_src + E);    // N*128 (reused as h2: N*64)
    float* h1      = h + (size_t)N * 128;      // N*128
    float* h2      = h;

    const int nb = (N + 1023) / 1024;

    hipMemsetAsync(deg, 0, (size_t)N * sizeof(int), stream);
    deg_count_kernel<<<(E + 255) / 256, 256, 0, stream>>>(tgt, deg, E);
    dinv_kernel<<<(N + 255) / 256, 256, 0, stream>>>(deg, dinv, N);

    // CSR build
    scan_partial<<<nb, 256, 0, stream>>>(deg, bsum, N);
    scan_bsum<<<1, 128, 0, stream>>>(bsum, nb);
    scan_final<<<nb, 256, 0, stream>>>(deg, bsum, rowptr, N, E);
    init_cursor<<<(N + 255) / 256, 256, 0, stream>>>(rowptr, cursor, N);
    fill_csr<<<(E + 255) / 256, 256, 0, stream>>>(src, tgt, cursor, csr_src, E);

    // Layer 1
    gemm_fp32<128, 32><<<(N + 31) / 32, 256, 0, stream>>>(x, W1, h, N);
    gather_kernel<128, true><<<(N + 3) / 4, 256, 0, stream>>>(
        h, rowptr, csr_src, dinv, b1, h1, N);

    // Layer 2
    gemm_fp32<64, 64><<<(N + 63) / 64, 256, 0, stream>>>(h1, W2, h2, N);
    gather_kernel<64, false><<<(N + 3) / 4, 256, 0, stream>>>(
        h2, rowptr, csr_src, dinv, b2, out, N);
}

// Round 3
// 518.877 us; speedup vs baseline: 8.1697x; 1.2029x over previous
//
#include <hip/hip_runtime.h>

// ---------------------------------------------------------------------------
// 2-layer GCN forward, pull-mode, bf16 gather tables.
//
//   deg count -> fused scan (rowptr+cursor+dinv) -> fill CSR
//   GEMM1 fp32 compute, bf16 output h          [N,128]
//   gather1: 16 lanes/row, 4 edges/wave-instr, fp32 acc, fused self+bias+relu
//   GEMM2 fp32 compute (fp32 h1 in), bf16 output h2 [N,64]
//   gather2: 8 lanes/row, 8 edges/wave-instr, fused self+bias
//
// ws layout (4-byte units): dinv[N] deg[N] rowptr[N+4] cursor[N] bsum[128]
//   csr_src[E] | h ushort[N*128] (reused as h2 ushort[N*64]) | h1 float[N*128]
// ---------------------------------------------------------------------------

typedef unsigned int uint;
typedef unsigned short ushort;

__device__ inline ushort f2bf(float f) {
    uint u = __float_as_uint(f);
    return (ushort)((u + 0x7fffu + ((u >> 16) & 1u)) >> 16);  // RNE
}
__device__ inline float bf_lo(uint u) { return __uint_as_float(u << 16); }
__device__ inline float bf_hi(uint u) { return __uint_as_float(u & 0xffff0000u); }

__global__ void deg_count_kernel(const int* __restrict__ tgt, int* __restrict__ deg, int E) {
    int t = blockIdx.x * blockDim.x + threadIdx.x;
    if (t < E) atomicAdd(&deg[tgt[t]], 1);
}

// ---- scan: deg -> rowptr (exclusive), fused cursor init + dinv compute ----
__global__ __launch_bounds__(256) void scan_partial(const int* __restrict__ deg,
                                                    int* __restrict__ bsum, int N) {
    int t = threadIdx.x, b = blockIdx.x;
    int base = b * 1024 + t * 4;
    int s = 0;
#pragma unroll
    for (int k = 0; k < 4; ++k) s += (base + k < N) ? deg[base + k] : 0;
#pragma unroll
    for (int off = 32; off > 0; off >>= 1) s += __shfl_down(s, off, 64);
    __shared__ int ws[4];
    if ((t & 63) == 0) ws[t >> 6] = s;
    __syncthreads();
    if (t == 0) bsum[b] = ws[0] + ws[1] + ws[2] + ws[3];
}

__global__ void scan_bsum(int* __restrict__ bsum, int nb) {
    __shared__ int s[128];
    int t = threadIdx.x;  // 128 threads
    int v = (t < nb) ? bsum[t] : 0;
    s[t] = v;
    __syncthreads();
    for (int off = 1; off < 128; off <<= 1) {
        int u = (t >= off) ? s[t - off] : 0;
        __syncthreads();
        s[t] += u;
        __syncthreads();
    }
    if (t < nb) bsum[t] = s[t] - v;  // exclusive
}

__global__ __launch_bounds__(256) void scan_final(const int* __restrict__ deg,
                                                  const int* __restrict__ bsum,
                                                  int* __restrict__ rowptr,
                                                  int* __restrict__ cursor,
                                                  float* __restrict__ dinv, int N, int E) {
    int t = threadIdx.x, b = blockIdx.x;
    int base = b * 1024 + t * 4;
    int d[4];
#pragma unroll
    for (int k = 0; k < 4; ++k) d[k] = (base + k < N) ? deg[base + k] : 0;
    int tot = d[0] + d[1] + d[2] + d[3];
    int incl = tot;
    int lane = t & 63, wid = t >> 6;
#pragma unroll
    for (int off = 1; off < 64; off <<= 1) {
        int u = __shfl_up(incl, off, 64);
        if (lane >= off) incl += u;
    }
    __shared__ int wsum[4];
    if (lane == 63) wsum[wid] = incl;
    __syncthreads();
    int woff = 0;
    for (int w = 0; w < wid; ++w) woff += wsum[w];
    int run = incl - tot + woff + bsum[b];
#pragma unroll
    for (int k = 0; k < 4; ++k) {
        if (base + k < N) {
            rowptr[base + k] = run;
            cursor[base + k] = run;
            dinv[base + k] = rsqrtf((float)d[k] + 1.0f);  // +1 self-loop
        }
        run += d[k];
    }
    if (b == gridDim.x - 1 && t == 255) rowptr[N] = E;
}

__global__ void fill_csr(const int* __restrict__ src, const int* __restrict__ tgt,
                         int* __restrict__ cursor, int* __restrict__ csr_src, int E) {
    int t = blockIdx.x * blockDim.x + threadIdx.x;
    if (t < E) {
        int pos = atomicAdd(&cursor[tgt[t]], 1);
        csr_src[pos] = src[t];
    }
}

// ---- C[N,M](bf16) = A[N,128](fp32) @ W[128,M](fp32); 4x4 fp32 microtile ----
template <int M, int ROWS>
__global__ __launch_bounds__(256) void gemm_fp32(const float* __restrict__ A,
                                                 const float* __restrict__ W,
                                                 ushort* __restrict__ C, int N) {
    __shared__ float wS[64 * M];
    __shared__ float aT[64 * ROWS];
    const int tid  = threadIdx.x;
    const int row0 = blockIdx.x * ROWS;
    const int c4   = (tid % (M / 4)) * 4;
    const int r0   = (tid / (M / 4)) * 4;
    float acc[4][4] = {};

    for (int kt = 0; kt < 128; kt += 64) {
        for (int i = tid * 4; i < 64 * M; i += 256 * 4)
            *(float4*)&wS[i] = *(const float4*)&W[(kt + i / M) * M + (i % M)];
        for (int i = tid * 4; i < ROWS * 64; i += 256 * 4) {
            int r = i / 64, k = i % 64;
            int row = row0 + r;
            if (row >= N) row = N - 1;
            float4 a = *(const float4*)&A[row * 128 + kt + k];
            aT[(k + 0) * ROWS + r] = a.x;
            aT[(k + 1) * ROWS + r] = a.y;
            aT[(k + 2) * ROWS + r] = a.z;
            aT[(k + 3) * ROWS + r] = a.w;
        }
        __syncthreads();
#pragma unroll 16
        for (int k = 0; k < 64; ++k) {
            float4 av = *(const float4*)&aT[k * ROWS + r0];
            float4 wv = *(const float4*)&wS[k * M + c4];
            float a4[4] = {av.x, av.y, av.z, av.w};
            float w4[4] = {wv.x, wv.y, wv.z, wv.w};
#pragma unroll
            for (int i = 0; i < 4; ++i)
#pragma unroll
                for (int j = 0; j < 4; ++j) acc[i][j] += a4[i] * w4[j];
        }
        __syncthreads();
    }
#pragma unroll
    for (int i = 0; i < 4; ++i) {
        int row = row0 + r0 + i;
        if (row < N) {
            ushort4 v;
            v.x = f2bf(acc[i][0]); v.y = f2bf(acc[i][1]);
            v.z = f2bf(acc[i][2]); v.w = f2bf(acc[i][3]);
            *(ushort4*)&C[(size_t)row * M + c4] = v;
        }
    }
}

// ---- pull gather, bf16 table.  Q=D/8 lanes per row, G=64/Q edge slots. ----
template <int D, bool RELU>
__global__ __launch_bounds__(256) void gather_kernel(
    const ushort* __restrict__ h, const int* __restrict__ rowptr,
    const int* __restrict__ csr_src, const float* __restrict__ dinv,
    const float* __restrict__ bias, float* __restrict__ out, int N) {
    constexpr int Q = D / 8;   // lanes covering one row (16B bf16x8 per lane)
    constexpr int G = 64 / Q;  // concurrent edge slots per wave
    const int wid = threadIdx.x >> 6, lane = threadIdx.x & 63;
    const int node = blockIdx.x * 4 + wid;
    if (node >= N) return;
    const int g = lane / Q, q = lane % Q;
    const int qoff = q * 8;
    const int beg = rowptr[node], end = rowptr[node + 1];
    float acc[8] = {};

    for (int j = beg; j < end; j += 2 * G) {  // 2 independent chains in flight
        int e0 = j + g, e1 = j + G + g;
        {
            bool v = e0 < end;
            int s = v ? csr_src[e0] : node;
            float w = v ? dinv[s] : 0.0f;
            uint4 hv = *(const uint4*)&h[(size_t)s * D + qoff];
            acc[0] += w * bf_lo(hv.x); acc[1] += w * bf_hi(hv.x);
            acc[2] += w * bf_lo(hv.y); acc[3] += w * bf_hi(hv.y);
            acc[4] += w * bf_lo(hv.z); acc[5] += w * bf_hi(hv.z);
            acc[6] += w * bf_lo(hv.w); acc[7] += w * bf_hi(hv.w);
        }
        {
            bool v = e1 < end;
            int s = v ? csr_src[e1] : node;
            float w = v ? dinv[s] : 0.0f;
            uint4 hv = *(const uint4*)&h[(size_t)s * D + qoff];
            acc[0] += w * bf_lo(hv.x); acc[1] += w * bf_hi(hv.x);
            acc[2] += w * bf_lo(hv.y); acc[3] += w * bf_hi(hv.y);
            acc[4] += w * bf_lo(hv.z); acc[5] += w * bf_hi(hv.z);
            acc[6] += w * bf_lo(hv.w); acc[7] += w * bf_hi(hv.w);
        }
    }
    // reduce across the G edge slots
#pragma unroll
    for (int m = Q; m < 64; m <<= 1)
#pragma unroll
        for (int k = 0; k < 8; ++k) acc[k] += __shfl_xor(acc[k], m, 64);

    const float di = dinv[node];
    {   // self-loop
        uint4 hv = *(const uint4*)&h[(size_t)node * D + qoff];
        acc[0] += di * bf_lo(hv.x); acc[1] += di * bf_hi(hv.x);
        acc[2] += di * bf_lo(hv.y); acc[3] += di * bf_hi(hv.y);
        acc[4] += di * bf_lo(hv.z); acc[5] += di * bf_hi(hv.z);
        acc[6] += di * bf_lo(hv.w); acc[7] += di * bf_hi(hv.w);
    }
    if (g == 0) {
        float4 b0 = *(const float4*)&bias[qoff];
        float4 b1 = *(const float4*)&bias[qoff + 4];
        float r[8] = {di * acc[0] + b0.x, di * acc[1] + b0.y,
                      di * acc[2] + b0.z, di * acc[3] + b0.w,
                      di * acc[4] + b1.x, di * acc[5] + b1.y,
                      di * acc[6] + b1.z, di * acc[7] + b1.w};
        if (RELU) {
#pragma unroll
            for (int k = 0; k < 8; ++k) r[k] = fmaxf(r[k], 0.0f);
        }
        *(float4*)&out[(size_t)node * D + qoff]     = make_float4(r[0], r[1], r[2], r[3]);
        *(float4*)&out[(size_t)node * D + qoff + 4] = make_float4(r[4], r[5], r[6], r[7]);
    }
}

extern "C" void kernel_launch(void* const* d_in, const int* in_sizes, int n_in,
                              void* d_out, int out_size, void* d_ws, size_t ws_size,
                              hipStream_t stream) {
    const float* x  = (const float*)d_in[0];
    const int*   ei = (const int*)d_in[1];
    const float* W1 = (const float*)d_in[2];
    const float* b1 = (const float*)d_in[3];
    const float* W2 = (const float*)d_in[4];
    const float* b2 = (const float*)d_in[5];
    float* out = (float*)d_out;

    const int N = in_sizes[0] / 128;
    const int E = in_sizes[1] / 2;
    const int* src = ei;
    const int* tgt = ei + E;

    float* ws      = (float*)d_ws;
    const size_t Np = (size_t)((N + 3) & ~3);  // keep 16B alignment of regions
    float*  dinv    = ws;                      // Np
    int*    deg     = (int*)(ws + Np);         // Np
    int*    rowptr  = deg + Np;                // Np+4
    int*    cursor  = rowptr + Np + 4;         // Np
    int*    bsum    = cursor + Np;             // 128
    int*    csr_src = bsum + 128;              // E (E mult of 4)
    ushort* h       = (ushort*)(csr_src + E);  // N*128 bf16 (reused as h2: N*64)
    float*  h1      = (float*)(h + (size_t)N * 128);  // N*128 fp32
    ushort* h2      = h;

    const int nb = (N + 1023) / 1024;

    hipMemsetAsync(deg, 0, (size_t)N * sizeof(int), stream);
    deg_count_kernel<<<(E + 255) / 256, 256, 0, stream>>>(tgt, deg, E);
    scan_partial<<<nb, 256, 0, stream>>>(deg, bsum, N);
    scan_bsum<<<1, 128, 0, stream>>>(bsum, nb);
    scan_final<<<nb, 256, 0, stream>>>(deg, bsum, rowptr, cursor, dinv, N, E);
    fill_csr<<<(E + 255) / 256, 256, 0, stream>>>(src, tgt, cursor, csr_src, E);

    // Layer 1
    gemm_fp32<128, 32><<<(N + 31) / 32, 256, 0, stream>>>(x, W1, h, N);
    gather_kernel<128, true><<<(N + 3) / 4, 256, 0, stream>>>(
        h, rowptr, csr_src, dinv, b1, h1, N);

    // Layer 2
    gemm_fp32<64, 64><<<(N + 63) / 64, 256, 0, stream>>>(h1, W2, h2, N);
    gather_kernel<64, false><<<(N + 3) / 4, 256, 0, stream>>>(
        h2, rowptr, csr_src, dinv, b2, out, N);
}